// Round 13
// baseline (221.722 us; speedup 1.0000x reference)
//
#include <hip/hip_runtime.h>

#define NTOK 4096
#define DIMC 1024
#define HEADS 12
#define DH 8
#define QSCALE 0.35355339059327373f   /* 8^-0.5 */
#define LOG2E  1.4426950408889634f
#define LN2    0.6931471805599453f
#define QPRE   (QSCALE * LOG2E)       /* fold log2e into q prescale */

typedef float f4 __attribute__((ext_vector_type(4)));
typedef float f2 __attribute__((ext_vector_type(2)));

// ws layout (floats):
//   Q:  [h][n][8]        (pre-scaled by QPRE), offset 0,    12*4096*8
//   K:  [h][16][8][256]  chunk-tiled SoA,      offset KOFF, 12*8*4096
#define KOFF (HEADS * NTOK * DH)

// ---------------- Kernel 1: proj = x @ W^T -> q (AoS, scaled), k (tiled) ---
__global__ __launch_bounds__(256) void k1_proj(const float* __restrict__ x,
                                               const float* __restrict__ W,
                                               float* __restrict__ qk) {
    __shared__ float xs[8 * 1028];         // pad 1024->1028 breaks bank aliasing
    const int t = threadIdx.x;
    const int row0 = blockIdx.x * 8;

    const f4* x4 = (const f4*)(x + (size_t)row0 * DIMC);
    #pragma unroll
    for (int i = 0; i < 8; ++i) {
        int f = t + i * 256;
        int r = f >> 8;
        int c4 = f & 255;
        f4 v = x4[f];
        *(f4*)(&xs[r * 1028 + c4 * 4]) = v;
    }
    __syncthreads();

    const int g  = t >> 2;                 // 0..63 -> owns o = 3g..3g+2
    const int rg = t & 3;                  // owns rows rg*2 .. rg*2+1

    f2 acc[2][3];
    #pragma unroll
    for (int a = 0; a < 2; ++a)
        #pragma unroll
        for (int m = 0; m < 3; ++m) acc[a][m] = (f2)(0.f);

    const float* w0 = W + (size_t)(3 * g) * DIMC;
    #pragma unroll 2
    for (int c = 0; c < DIMC; c += 4) {
        f4 w[3];
        #pragma unroll
        for (int m = 0; m < 3; ++m)
            w[m] = *(const f4*)(w0 + (size_t)m * DIMC + c);
        #pragma unroll
        for (int a = 0; a < 2; ++a) {
            f4 xv = *(const f4*)(&xs[(rg * 2 + a) * 1028 + c]);
            #pragma unroll
            for (int m = 0; m < 3; ++m) {
                acc[a][m] = __builtin_elementwise_fma(xv.xy, w[m].xy, acc[a][m]);
                acc[a][m] = __builtin_elementwise_fma(xv.zw, w[m].zw, acc[a][m]);
            }
        }
    }

    #pragma unroll
    for (int m = 0; m < 3; ++m) {
        int o   = 3 * g + m;
        int qkf = (o >= 96) ? 1 : 0;
        int oo  = o - 96 * qkf;
        int h   = oo >> 3;
        int d   = oo & 7;
        #pragma unroll
        for (int a = 0; a < 2; ++a) {
            int n = row0 + rg * 2 + a;
            float v = acc[a][m].x + acc[a][m].y;
            if (!qkf) {
                qk[((size_t)h * NTOK + n) * DH + d] = v * QPRE;        // Q AoS
            } else {
                qk[KOFF + (((size_t)h * 16 + (n >> 8)) * DH + d) * 256 + (n & 255)] = v;
            }
        }
    }
}

// ---------------- Kernel 2: ONE ROW PER BLOCK, 8 waves = 8 chunks ----------
// Block writes one contiguous 8 KB window per half-row -> few, long, dense
// HBM write streams per CU (fillBuffer-like) instead of 16-32 strided ones.
__device__ __forceinline__ float lsig2(float u) {
    // logsigmoid in log2 units: min(u,0) - log2(1 + 2^-|u|)   (u = s*log2e)
    float mn = fminf(u, 0.f);
    float z  = __builtin_amdgcn_exp2f(-fabsf(u));   // -|u| is a free modifier
    return mn - __builtin_amdgcn_logf(1.f + z);     // v_log_f32 = log2
}

__global__ __launch_bounds__(512) void k2_gates(const float* __restrict__ qk,
                                                float* __restrict__ out) {
    const int bid  = blockIdx.x;
    const int h    = bid >> 12;             // 4096 blocks per head
    const int r    = bid & (NTOK - 1);      // this block's row
    const int t    = threadIdx.x;
    const int lane = t & 63;
    const int wid  = t >> 6;                // 0..7

    __shared__ float wt[2][8];              // per-half wave totals

    // q row (block-uniform -> scalar loads)
    const float* qp = qk + ((size_t)h * NTOK + r) * DH;
    float q[8];
    #pragma unroll
    for (int d = 0; d < 8; ++d) q[d] = qp[d];

    const float* kh = qk + KOFF + (size_t)h * (16 * DH * 256) + 4 * lane;
    float* o = out + ((size_t)h * NTOK + r) * NTOK;
    const int cb = r >> 8;                  // boundary chunk

    const f4 z = (f4)(0.f);
    float carry = 0.f;                      // identical value in all waves

    #pragma unroll
    for (int half = 1; half >= 0; --half) {
        const int cc = half * 8 + wid;      // this wave's chunk
        const int j0 = cc * 256 + 4 * lane;
        const bool live = (cc <= cb);

        f4 gv = z;
        float tot = 0.f, s = 0.f, wtotal = 0.f;

        if (live) {
            const float* kc = kh + (size_t)cc * 2048;
            f4 kv[8];
            #pragma unroll
            for (int d = 0; d < 8; ++d) kv[d] = *(const f4*)(kc + d * 256);

            f2 A = (f2)(0.f), B = (f2)(0.f);
            #pragma unroll
            for (int d = 0; d < 8; ++d) {
                A = __builtin_elementwise_fma(kv[d].xy, (f2)(q[d]), A);
                B = __builtin_elementwise_fma(kv[d].zw, (f2)(q[d]), B);
            }

            float g0, g1, g2, g3;
            if (cc == cb) {                  // boundary: mask j < r
                g0 = (j0 + 0 < r) ? lsig2(A.x) : 0.f;
                g1 = (j0 + 1 < r) ? lsig2(A.y) : 0.f;
                g2 = (j0 + 2 < r) ? lsig2(B.x) : 0.f;
                g3 = (j0 + 3 < r) ? lsig2(B.y) : 0.f;
            } else {                         // interior: all j < r
                g0 = lsig2(A.x); g1 = lsig2(A.y);
                g2 = lsig2(B.x); g3 = lsig2(B.y);
            }

            g2 += g3; g1 += g2; g0 += g1;    // local reverse suffix
            tot = g0;
            s = tot;
            #pragma unroll
            for (int off = 1; off < 64; off <<= 1) {
                float v = __shfl_down(s, off, 64);
                if (lane + off < 64) s += v;
            }
            wtotal = __builtin_amdgcn_readfirstlane(s);   // chunk total
            gv.x = g0; gv.y = g1; gv.z = g2; gv.w = g3;
        }

        if (lane == 0) wt[half][wid] = live ? wtotal : 0.f;
        __syncthreads();

        // inter-wave suffix base + running carry (same in all waves)
        float ib = carry, tot8 = 0.f;
        #pragma unroll
        for (int w2 = 0; w2 < 8; ++w2) {
            float v = wt[half][w2];
            tot8 += v;
            if (w2 > wid) ib += v;
        }
        carry += tot8;

        f4 ov = live ? ((gv + ((s - tot) + ib)) * LN2) : z;
        __builtin_nontemporal_store(ov, (f4*)(o + j0));
    }
}

extern "C" void kernel_launch(void* const* d_in, const int* in_sizes, int n_in,
                              void* d_out, int out_size, void* d_ws, size_t ws_size,
                              hipStream_t stream) {
    const float* x = (const float*)d_in[0];
    const float* W = (const float*)d_in[1];
    float* out = (float*)d_out;
    float* qk  = (float*)d_ws;               // 3 MB scratch

    hipLaunchKernelGGL(k1_proj, dim3(NTOK / 8), dim3(256), 0, stream, x, W, qk);
    hipLaunchKernelGGL(k2_gates, dim3(HEADS * NTOK), dim3(512), 0, stream, qk, out);
}